// Round 14
// baseline (322.778 us; speedup 1.0000x reference)
//
#include <hip/hip_runtime.h>
#include <hip/hip_bf16.h>
#include <stdint.h>

typedef __bf16 bf16;
typedef __bf16 bf16x8 __attribute__((ext_vector_type(8)));
typedef __bf16 bf16x4 __attribute__((ext_vector_type(4)));
typedef float f32x4 __attribute__((ext_vector_type(4)));

#define N_TOK 4096
#define DDIM 1024
#define HDIM 2048
#define NPAIR 8192

__device__ __forceinline__ void gload16(const void* g, void* l) {
  __builtin_amdgcn_global_load_lds(
      (const __attribute__((address_space(1))) unsigned int*)g,
      (__attribute__((address_space(3))) unsigned int*)l, 16, 0, 0);
}

// ------- per-expert transpose+convert: in [R][C] f32 -> out [C][R] bf16 -------
__global__ void transpose_cvt_kernel(const float* __restrict__ in, bf16* __restrict__ out,
                                     int R, int C) {
  __shared__ float tile[32][33];
  const float* ip = in + (size_t)blockIdx.z * R * C;
  bf16* op = out + (size_t)blockIdx.z * R * C;
  int r0 = blockIdx.y * 32, c0 = blockIdx.x * 32;
  int tr = threadIdx.x >> 3;
  int tc = (threadIdx.x & 7) * 4;
  float4 v = *(const float4*)(ip + (size_t)(r0 + tr) * C + c0 + tc);
  tile[tr][tc] = v.x; tile[tr][tc + 1] = v.y; tile[tr][tc + 2] = v.z; tile[tr][tc + 3] = v.w;
  __syncthreads();
  bf16x4 o = {(bf16)tile[tc + 0][tr], (bf16)tile[tc + 1][tr],
              (bf16)tile[tc + 2][tr], (bf16)tile[tc + 3][tr]};
  *(bf16x4*)(op + (size_t)(c0 + tr) * R + r0 + tc) = o;
}

// -- gating: fp32 logits, softmax, top-2; emits xb; zeroes y2a/y2b partials --
__global__ void gate_kernel(const float* __restrict__ x, const float* __restrict__ Wg,
                            int2* __restrict__ ge, float2* __restrict__ gp,
                            bf16* __restrict__ xb, float* __restrict__ y2a,
                            float* __restrict__ y2b) {
  int t0 = blockIdx.x * 4;
  {
    float4 z = make_float4(0.f, 0.f, 0.f, 0.f);
    float4* za = (float4*)(y2a + (size_t)t0 * DDIM);
    float4* zb = (float4*)(y2b + (size_t)t0 * DDIM);
#pragma unroll
    for (int r = 0; r < 4; r++) {
      za[r * 256 + threadIdx.x] = z;
      zb[r * 256 + threadIdx.x] = z;
    }
  }
  int t = t0 + (threadIdx.x >> 6);
  int lane = threadIdx.x & 63;
  const float* xr = x + (size_t)t * DDIM;
  bf16* xbr = xb + (size_t)t * DDIM;
  float a[8];
#pragma unroll
  for (int e = 0; e < 8; e++) a[e] = 0.f;
#pragma unroll
  for (int it = 0; it < 4; it++) {
    int d0 = it * 256 + lane * 4;
    float4 xv = *(const float4*)(xr + d0);
    bf16x4 o = {(bf16)xv.x, (bf16)xv.y, (bf16)xv.z, (bf16)xv.w};
    *(bf16x4*)(xbr + d0) = o;
    float xs[4] = {xv.x, xv.y, xv.z, xv.w};
#pragma unroll
    for (int dd = 0; dd < 4; dd++) {
      float4 w0 = *(const float4*)(Wg + (size_t)(d0 + dd) * 8);
      float4 w1 = *(const float4*)(Wg + (size_t)(d0 + dd) * 8 + 4);
      a[0] += xs[dd] * w0.x; a[1] += xs[dd] * w0.y; a[2] += xs[dd] * w0.z; a[3] += xs[dd] * w0.w;
      a[4] += xs[dd] * w1.x; a[5] += xs[dd] * w1.y; a[6] += xs[dd] * w1.z; a[7] += xs[dd] * w1.w;
    }
  }
#pragma unroll
  for (int off = 32; off >= 1; off >>= 1) {
#pragma unroll
    for (int e = 0; e < 8; e++) a[e] += __shfl_xor(a[e], off);
  }
  if (lane == 0) {
    float m = a[0];
#pragma unroll
    for (int e = 1; e < 8; e++) m = fmaxf(m, a[e]);
    float p[8]; float s = 0.f;
#pragma unroll
    for (int e = 0; e < 8; e++) { p[e] = expf(a[e] - m); s += p[e]; }
    float inv = 1.f / s;
    int i0 = 0; float v0 = a[0];
#pragma unroll
    for (int e = 1; e < 8; e++) if (a[e] > v0) { v0 = a[e]; i0 = e; }
    int i1 = -1; float v1 = -1e30f;
#pragma unroll
    for (int e = 0; e < 8; e++) if (e != i0 && a[e] > v1) { v1 = a[e]; i1 = e; }
    ge[t] = make_int2(i0, i1);
    gp[t] = make_float2(p[i0] * inv, p[i1] * inv);
  }
}

// ------- deterministic stable counting sort of 8192 pairs by expert (1 block) -------
// meta[0..8]=segment base; meta[9..16]=tileStart (BM=128), meta[17]=total128
__global__ void sort_kernel(const int2* __restrict__ ge, const float2* __restrict__ gp,
                            int* __restrict__ tok, float* __restrict__ ps,
                            int* __restrict__ meta) {
  __shared__ int hist[8], runn[8], wc[16][8], wb[16][8], baseS[9];
  int tid = threadIdx.x;
  int lane = tid & 63, wv = tid >> 6;
  if (tid < 8) hist[tid] = 0;
  __syncthreads();
  for (int i = tid; i < NPAIR; i += 1024) {
    int2 g = ge[i >> 1];
    int e = (i & 1) ? g.y : g.x;
    atomicAdd(&hist[e], 1);
  }
  __syncthreads();
  if (tid == 0) {
    int b = 0, ts1 = 0;
    for (int e = 0; e < 8; e++) {
      baseS[e] = b; meta[e] = b;
      meta[9 + e] = ts1;  ts1 += (hist[e] + 127) / 128;
      b += hist[e];
    }
    baseS[8] = b; meta[8] = b; meta[17] = ts1;
  }
  __syncthreads();
  if (tid < 8) runn[tid] = baseS[tid];
  __syncthreads();
  for (int c = 0; c < 8; c++) {
    int i = c * 1024 + tid;
    int2 g = ge[i >> 1];
    int e = (i & 1) ? g.y : g.x;
    int rank = 0;
#pragma unroll
    for (int ee = 0; ee < 8; ee++) {
      unsigned long long b = __ballot(e == ee);
      if (e == ee) rank = __popcll(b & ((1ull << lane) - 1ull));
      if (lane == 0) wc[wv][ee] = __popcll(b);
    }
    __syncthreads();
    if (tid < 8) {
      int s = runn[tid];
      for (int w = 0; w < 16; w++) { wb[w][tid] = s; s += wc[w][tid]; }
      runn[tid] = s;
    }
    __syncthreads();
    int pos = wb[wv][e] + rank;
    tok[pos] = i >> 1;
    float2 p2 = gp[i >> 1];
    ps[pos] = (i & 1) ? p2.y : p2.x;
    __syncthreads();
  }
}

// ---- grouped GEMM: BM=128, BN=128, BK=32, 256 thr (4 waves 2x2) ----
// R14: B operand DIRECT global->register (skips LDS). Each lane's B-fragment
// is 8 contiguous bf16 along K = one global_load_dwordx4 from the L2-resident
// weight panel. Halves gload_lds staging (4->2), LDS frag reads (8->4), and
// barrier-drain volume — the two components R12's ablation measured as the
// cost (LDS +24us, staging +29us). A stays LDS-staged (tok[] gather needs the
// coalescing round-trip). Plain m97 loop, no inline asm.
// G2 runs as split-K2 (NT=16: 8 n-tiles x 2 k-halves) into y2a/y2b (2
// commutative atomics/elem -> bit-deterministic), combined afterwards.
// FIRST: A=xb[tok[row]], B=W1T -> h = relu(A*B + b1), bf16
// !FIRST: A=hbuf,        B=W2T -> atomicAdd(y2{a,b}[tok[row]], (A*B + b2?)*ps)
template <bool FIRST>
__global__ __launch_bounds__(256, 3)
void moe_gemm_kernel(const bf16* __restrict__ A, const bf16* __restrict__ Bt,
                     const float* __restrict__ bias, const int* __restrict__ tok,
                     const float* __restrict__ ps, const int* __restrict__ meta,
                     bf16* __restrict__ hout, float* __restrict__ y2a,
                     float* __restrict__ y2b) {
  constexpr int AKst = FIRST ? DDIM : HDIM;   // A row stride
  constexpr int BKst = FIRST ? DDIM : HDIM;   // B row stride
  constexpr int NPE  = FIRST ? HDIM : DDIM;   // B rows per expert (= N)
  constexpr int NT   = 16;                    // G1: 16 n-tiles; G2: 8 n x 2 k
  constexpr int nk   = 32;                    // K = 1024 per (half-)dispatch
  __shared__ bf16 lds[2][4096];               // A only: 128x32 per buffer

  // runtime-balanced XCD-chunked mapping
  int MTa = meta[17];
  int xcd = blockIdx.x & 7;
  int idx = blockIdx.x >> 3;
  int mLo = (MTa * xcd) >> 3;
  int mHi = (MTa * (xcd + 1)) >> 3;
  int cnt = mHi - mLo;
  if (idx >= cnt * NT) return;
  int tileN = idx / cnt;
  int tileM = mLo + idx - tileN * cnt;

  int e = 0;
#pragma unroll
  for (int k = 1; k < 8; k++) if (tileM >= meta[9 + k]) e = k;
  int row0 = meta[e] + (tileM - meta[9 + e]) * 128;
  int segEnd = meta[e + 1];
  int n0, kOff;
  if (FIRST) { n0 = tileN * 128; kOff = 0; }
  else       { n0 = (tileN & 7) * 128; kOff = (tileN >> 3) * 1024; }

  int t = threadIdx.x;
  // A staging: round r -> LDS row r*64+(t>>2), dest 16B-chunk t&3 (linear);
  // pre-swizzle SOURCE chunk: c' = (t&3) ^ ((row>>1)&3) = (t&3) ^ ((t>>3)&3)
  const bf16* aSrc[2];
  {
    int swz = ((t & 3) ^ ((t >> 3) & 3)) * 8;
#pragma unroll
    for (int r = 0; r < 2; r++) {
      int row = r * 64 + (t >> 2);
      int gRow = row0 + row; if (gRow > NPAIR - 1) gRow = NPAIR - 1;
      int arow = FIRST ? tok[gRow] : gRow;
      aSrc[r] = A + (size_t)arow * AKst + kOff + swz;
    }
  }

  int lane = t & 63, wv = t >> 6;
  int wm = wv >> 1, wn = wv & 1;  // 2x2 waves; per-wave out 64x64
  int l15 = lane & 15, l4 = lane >> 4;
  int aOff[4];
#pragma unroll
  for (int m = 0; m < 4; m++) {
    int row = wm * 64 + m * 16 + l15;
    aOff[m] = row * 32 + ((l4 ^ ((row >> 1) & 3)) * 8);
  }
  // B fragments direct from global: lane reads Bt row (n0+wn*64+n*16+l15),
  // k-chunk l4*8 — 16 rows x 64B per wave-instruction, L2-resident panel.
  const bf16* bBase[4];
#pragma unroll
  for (int n = 0; n < 4; n++) {
    int row = wn * 64 + n * 16 + l15;
    bBase[n] = Bt + ((size_t)e * NPE + n0 + row) * BKst + kOff + l4 * 8;
  }

  f32x4 acc[4][4];
#pragma unroll
  for (int m = 0; m < 4; m++)
#pragma unroll
    for (int n = 0; n < 4; n++)
#pragma unroll
      for (int j = 0; j < 4; j++) acc[m][n][j] = 0.f;

  auto STAGE_A = [&](int kt, int buf) {
    bf16* sb = &lds[buf][0];
    int ko = kt * 32;
    gload16(aSrc[0] + ko, sb + t * 8);
    gload16(aSrc[1] + ko, sb + 2048 + t * 8);
  };

  STAGE_A(0, 0);
  __syncthreads();

  for (int kt = 0; kt < nk; kt++) {
    if (kt + 1 < nk) STAGE_A(kt + 1, (kt + 1) & 1);
    const bf16* sb = &lds[kt & 1][0];
    bf16x8 af[4], bfr[4];
#pragma unroll
    for (int n = 0; n < 4; n++) bfr[n] = *(const bf16x8*)(bBase[n] + kt * 32);
#pragma unroll
    for (int m = 0; m < 4; m++) af[m] = *(const bf16x8*)(sb + aOff[m]);
#pragma unroll
    for (int m = 0; m < 4; m++)
#pragma unroll
      for (int n = 0; n < 4; n++)
        acc[m][n] = __builtin_amdgcn_mfma_f32_16x16x32_bf16(af[m], bfr[n], acc[m][n], 0, 0, 0);
    __syncthreads();
  }

  int colb = n0 + wn * 64 + l15;
  int rowb = wm * 64 + l4 * 4;
  float bia[4];
#pragma unroll
  for (int n = 0; n < 4; n++)
    bia[n] = (FIRST || kOff == 0) ? bias[(size_t)e * NPE + colb + n * 16] : 0.f;
  float* ybuf = FIRST ? nullptr : ((kOff == 0) ? y2a : y2b);
#pragma unroll
  for (int m = 0; m < 4; m++) {
#pragma unroll
    for (int jj = 0; jj < 4; jj++) {
      int gRow = row0 + rowb + m * 16 + jj;
      if (gRow < segEnd) {
        if (FIRST) {
#pragma unroll
          for (int n = 0; n < 4; n++) {
            float v = acc[m][n][jj] + bia[n];
            v = fmaxf(v, 0.f);
            hout[(size_t)gRow * HDIM + colb + n * 16] = (bf16)v;
          }
        } else {
          float pscale = ps[gRow];
          float* orow = ybuf + (size_t)tok[gRow] * DDIM;
#pragma unroll
          for (int n = 0; n < 4; n++) {
            float v = (acc[m][n][jj] + bia[n]) * pscale;
            atomicAdd(orow + colb + n * 16, v);  // 2 adds/elem/buf -> deterministic
          }
        }
      }
    }
  }
}

// ---------------- combine: out = y2a + y2b ----------------
__global__ void combine_kernel(const float* __restrict__ a, const float* __restrict__ b,
                               float* __restrict__ out) {
  int i = blockIdx.x * 256 + threadIdx.x;
  f32x4 va = ((const f32x4*)a)[i];
  f32x4 vb = ((const f32x4*)b)[i];
  ((f32x4*)out)[i] = va + vb;
}

extern "C" void kernel_launch(void* const* d_in, const int* in_sizes, int n_in,
                              void* d_out, int out_size, void* d_ws, size_t ws_size,
                              hipStream_t stream) {
  (void)in_sizes; (void)n_in; (void)out_size; (void)ws_size;
  const float* x  = (const float*)d_in[0];
  const float* Wg = (const float*)d_in[1];
  const float* W1 = (const float*)d_in[2];
  const float* b1 = (const float*)d_in[3];
  const float* W2 = (const float*)d_in[4];
  const float* b2 = (const float*)d_in[5];
  float* out = (float*)d_out;

  char* ws = (char*)d_ws;
  bf16*  xb   = (bf16*)(ws);                     //   8 MiB: [4096][1024] bf16
  bf16*  W1T  = (bf16*)(ws + (8ull  << 20));     //  32 MiB: [8][2048][1024] bf16
  bf16*  W2T  = (bf16*)(ws + (40ull << 20));     //  32 MiB: [8][1024][2048] bf16
  bf16*  hbuf = (bf16*)(ws + (72ull << 20));     //  32 MiB: [8192][2048] bf16
  float* y2a  = (float*)(ws + (104ull << 20));   //  16 MiB: [4096][1024] f32
  float* y2b  = (float*)(ws + (120ull << 20));   //  16 MiB: [4096][1024] f32
  char*  ext  = ws + (136ull << 20);
  int2*   ge      = (int2*)(ext);
  float2* gp      = (float2*)(ext + (64u  << 10));
  int*    tok     = (int*)(ext + (128u << 10));
  float*  psarr   = (float*)(ext + (160u << 10));
  int*    meta    = (int*)(ext + (224u << 10));

  transpose_cvt_kernel<<<dim3(64, 32, 8), 256, 0, stream>>>(W1, W1T, 1024, 2048);
  transpose_cvt_kernel<<<dim3(32, 64, 8), 256, 0, stream>>>(W2, W2T, 2048, 1024);
  gate_kernel<<<1024, 256, 0, stream>>>(x, Wg, ge, gp, xb, y2a, y2b);
  sort_kernel<<<1, 1024, 0, stream>>>(ge, gp, tok, psarr, meta);
  // per-XCD M-slots = ceil(71/8) = 9; grid = 9 * 16 * 8 = 1152 for both
  moe_gemm_kernel<true><<<dim3(1152), 256, 0, stream>>>(
      xb, W1T, b1, tok, psarr, meta, hbuf, nullptr, nullptr);
  moe_gemm_kernel<false><<<dim3(1152), 256, 0, stream>>>(
      hbuf, W2T, b2, tok, psarr, meta, nullptr, y2a, y2b);
  combine_kernel<<<4096, 256, 0, stream>>>(y2a, y2b, out);
}

// Round 15
// 259.250 us; speedup vs baseline: 1.2450x; 1.2450x over previous
//
#include <hip/hip_runtime.h>
#include <hip/hip_bf16.h>
#include <stdint.h>

typedef __bf16 bf16;
typedef __bf16 bf16x8 __attribute__((ext_vector_type(8)));
typedef __bf16 bf16x4 __attribute__((ext_vector_type(4)));
typedef float f32x4 __attribute__((ext_vector_type(4)));

#define N_TOK 4096
#define DDIM 1024
#define HDIM 2048
#define NPAIR 8192

__device__ __forceinline__ void gload16(const void* g, void* l) {
  __builtin_amdgcn_global_load_lds(
      (const __attribute__((address_space(1))) unsigned int*)g,
      (__attribute__((address_space(3))) unsigned int*)l, 16, 0, 0);
}

// ------- per-expert transpose+convert: in [R][C] f32 -> out [C][R] bf16 -------
__global__ void transpose_cvt_kernel(const float* __restrict__ in, bf16* __restrict__ out,
                                     int R, int C) {
  __shared__ float tile[32][33];
  const float* ip = in + (size_t)blockIdx.z * R * C;
  bf16* op = out + (size_t)blockIdx.z * R * C;
  int r0 = blockIdx.y * 32, c0 = blockIdx.x * 32;
  int tr = threadIdx.x >> 3;
  int tc = (threadIdx.x & 7) * 4;
  float4 v = *(const float4*)(ip + (size_t)(r0 + tr) * C + c0 + tc);
  tile[tr][tc] = v.x; tile[tr][tc + 1] = v.y; tile[tr][tc + 2] = v.z; tile[tr][tc + 3] = v.w;
  __syncthreads();
  bf16x4 o = {(bf16)tile[tc + 0][tr], (bf16)tile[tc + 1][tr],
              (bf16)tile[tc + 2][tr], (bf16)tile[tc + 3][tr]};
  *(bf16x4*)(op + (size_t)(c0 + tr) * R + r0 + tc) = o;
}

// -- gating: fp32 logits, softmax, top-2; emits xb; zeroes y2a/y2b partials --
__global__ void gate_kernel(const float* __restrict__ x, const float* __restrict__ Wg,
                            int2* __restrict__ ge, float2* __restrict__ gp,
                            bf16* __restrict__ xb, float* __restrict__ y2a,
                            float* __restrict__ y2b) {
  int t0 = blockIdx.x * 4;
  {
    float4 z = make_float4(0.f, 0.f, 0.f, 0.f);
    float4* za = (float4*)(y2a + (size_t)t0 * DDIM);
    float4* zb = (float4*)(y2b + (size_t)t0 * DDIM);
#pragma unroll
    for (int r = 0; r < 4; r++) {
      za[r * 256 + threadIdx.x] = z;
      zb[r * 256 + threadIdx.x] = z;
    }
  }
  int t = t0 + (threadIdx.x >> 6);
  int lane = threadIdx.x & 63;
  const float* xr = x + (size_t)t * DDIM;
  bf16* xbr = xb + (size_t)t * DDIM;
  float a[8];
#pragma unroll
  for (int e = 0; e < 8; e++) a[e] = 0.f;
#pragma unroll
  for (int it = 0; it < 4; it++) {
    int d0 = it * 256 + lane * 4;
    float4 xv = *(const float4*)(xr + d0);
    bf16x4 o = {(bf16)xv.x, (bf16)xv.y, (bf16)xv.z, (bf16)xv.w};
    *(bf16x4*)(xbr + d0) = o;
    float xs[4] = {xv.x, xv.y, xv.z, xv.w};
#pragma unroll
    for (int dd = 0; dd < 4; dd++) {
      float4 w0 = *(const float4*)(Wg + (size_t)(d0 + dd) * 8);
      float4 w1 = *(const float4*)(Wg + (size_t)(d0 + dd) * 8 + 4);
      a[0] += xs[dd] * w0.x; a[1] += xs[dd] * w0.y; a[2] += xs[dd] * w0.z; a[3] += xs[dd] * w0.w;
      a[4] += xs[dd] * w1.x; a[5] += xs[dd] * w1.y; a[6] += xs[dd] * w1.z; a[7] += xs[dd] * w1.w;
    }
  }
#pragma unroll
  for (int off = 32; off >= 1; off >>= 1) {
#pragma unroll
    for (int e = 0; e < 8; e++) a[e] += __shfl_xor(a[e], off);
  }
  if (lane == 0) {
    float m = a[0];
#pragma unroll
    for (int e = 1; e < 8; e++) m = fmaxf(m, a[e]);
    float p[8]; float s = 0.f;
#pragma unroll
    for (int e = 0; e < 8; e++) { p[e] = expf(a[e] - m); s += p[e]; }
    float inv = 1.f / s;
    int i0 = 0; float v0 = a[0];
#pragma unroll
    for (int e = 1; e < 8; e++) if (a[e] > v0) { v0 = a[e]; i0 = e; }
    int i1 = -1; float v1 = -1e30f;
#pragma unroll
    for (int e = 0; e < 8; e++) if (e != i0 && a[e] > v1) { v1 = a[e]; i1 = e; }
    ge[t] = make_int2(i0, i1);
    gp[t] = make_float2(p[i0] * inv, p[i1] * inv);
  }
}

// ------- deterministic stable counting sort of 8192 pairs by expert (1 block) -------
// meta[0..8]=segment base; meta[9..16]=tileStart (BM=128), meta[17]=total128
__global__ void sort_kernel(const int2* __restrict__ ge, const float2* __restrict__ gp,
                            int* __restrict__ tok, float* __restrict__ ps,
                            int* __restrict__ meta) {
  __shared__ int hist[8], runn[8], wc[16][8], wb[16][8], baseS[9];
  int tid = threadIdx.x;
  int lane = tid & 63, wv = tid >> 6;
  if (tid < 8) hist[tid] = 0;
  __syncthreads();
  for (int i = tid; i < NPAIR; i += 1024) {
    int2 g = ge[i >> 1];
    int e = (i & 1) ? g.y : g.x;
    atomicAdd(&hist[e], 1);
  }
  __syncthreads();
  if (tid == 0) {
    int b = 0, ts1 = 0;
    for (int e = 0; e < 8; e++) {
      baseS[e] = b; meta[e] = b;
      meta[9 + e] = ts1;  ts1 += (hist[e] + 127) / 128;
      b += hist[e];
    }
    baseS[8] = b; meta[8] = b; meta[17] = ts1;
  }
  __syncthreads();
  if (tid < 8) runn[tid] = baseS[tid];
  __syncthreads();
  for (int c = 0; c < 8; c++) {
    int i = c * 1024 + tid;
    int2 g = ge[i >> 1];
    int e = (i & 1) ? g.y : g.x;
    int rank = 0;
#pragma unroll
    for (int ee = 0; ee < 8; ee++) {
      unsigned long long b = __ballot(e == ee);
      if (e == ee) rank = __popcll(b & ((1ull << lane) - 1ull));
      if (lane == 0) wc[wv][ee] = __popcll(b);
    }
    __syncthreads();
    if (tid < 8) {
      int s = runn[tid];
      for (int w = 0; w < 16; w++) { wb[w][tid] = s; s += wc[w][tid]; }
      runn[tid] = s;
    }
    __syncthreads();
    int pos = wb[wv][e] + rank;
    tok[pos] = i >> 1;
    float2 p2 = gp[i >> 1];
    ps[pos] = (i & 1) ? p2.y : p2.x;
    __syncthreads();
  }
}

// ---- grouped GEMM: 128x128 tile, BK=32, 128 thr = 2 WAVES, 4 blocks/CU ----
// R15: arithmetic-intensity via per-wave 64x128 output (acc[4][8], 128 VGPR,
// 43.7 FLOP/LDS-byte vs 32.8) while KEEPING many-small-blocks stagger (the
// ledger shows 1-blk/CU lockstep costs 1.5x per FLOP). Per block-iter: LDS
// reads 24KB (A private/wave 4KB, B shared-read 8KB x2 waves) for 1.05 MFLOP.
// m97-style no-asm loop (R13 proven). T2 swizzle, XCD-chunked map.
// FIRST: A=xb[tok[row]], B=W1T -> h = relu(A*B + b1), bf16. K=1024, NT=16.
// !FIRST: A=hbuf, B=W2T, K=2048 split-K2 (NT=16: 8 n x 2 k-halves) ->
//         atomicAdd(y2{a,b}[tok[row]], ...) ; 2 commutative adds/elem each.
template <bool FIRST>
__global__ __launch_bounds__(128, 2)
void moe_gemm_kernel(const bf16* __restrict__ A, const bf16* __restrict__ Bt,
                     const float* __restrict__ bias, const int* __restrict__ tok,
                     const float* __restrict__ ps, const int* __restrict__ meta,
                     bf16* __restrict__ hout, float* __restrict__ y2a,
                     float* __restrict__ y2b) {
  constexpr int AKst = FIRST ? DDIM : HDIM;   // A row stride
  constexpr int BKst = FIRST ? DDIM : HDIM;   // B row stride
  constexpr int NPE  = FIRST ? HDIM : DDIM;   // B rows per expert (= N)
  constexpr int NT   = 16;                    // G1: 16 n; G2: 8 n x 2 k
  constexpr int nk   = 32;                    // K = 1024 per (half-)dispatch
  __shared__ bf16 lds[2][8192];               // buf: A 128x32 | B 128x32

  // runtime-balanced XCD-chunked mapping
  int MTa = meta[17];
  int xcd = blockIdx.x & 7;
  int idx = blockIdx.x >> 3;
  int mLo = (MTa * xcd) >> 3;
  int mHi = (MTa * (xcd + 1)) >> 3;
  int cnt = mHi - mLo;
  if (idx >= cnt * NT) return;
  int tileN = idx / cnt;
  int tileM = mLo + idx - tileN * cnt;

  int e = 0;
#pragma unroll
  for (int k = 1; k < 8; k++) if (tileM >= meta[9 + k]) e = k;
  int row0 = meta[e] + (tileM - meta[9 + e]) * 128;
  int segEnd = meta[e + 1];
  int n0, kOff;
  if (FIRST) { n0 = tileN * 128; kOff = 0; }
  else       { n0 = (tileN & 7) * 128; kOff = (tileN >> 3) * 1024; }

  int t = threadIdx.x;  // 128 threads
  // staging: round r covers rows r*32+(t>>2), dest 16B-chunk t&3 (linear);
  // pre-swizzle SOURCE chunk: c' = (t&3) ^ ((row>>1)&3) = (t&3) ^ ((t>>3)&3)
  const bf16* aSrc[4];
  const bf16* bSrc[4];
  {
    int swz = ((t & 3) ^ ((t >> 3) & 3)) * 8;
#pragma unroll
    for (int r = 0; r < 4; r++) {
      int row = r * 32 + (t >> 2);
      int gRow = row0 + row; if (gRow > NPAIR - 1) gRow = NPAIR - 1;
      int arow = FIRST ? tok[gRow] : gRow;
      aSrc[r] = A + (size_t)arow * AKst + kOff + swz;
      bSrc[r] = Bt + ((size_t)e * NPE + n0 + row) * BKst + kOff + swz;
    }
  }

  int lane = t & 63, wm = t >> 6;  // 2 waves, wm = m-half; each wave N=full 128
  int l15 = lane & 15, l4 = lane >> 4;
  int aOff[4], bOff[8];
#pragma unroll
  for (int m = 0; m < 4; m++) {
    int row = wm * 64 + m * 16 + l15;
    aOff[m] = row * 32 + ((l4 ^ ((row >> 1) & 3)) * 8);
  }
#pragma unroll
  for (int n = 0; n < 8; n++) {
    int row = n * 16 + l15;
    bOff[n] = 4096 + row * 32 + ((l4 ^ ((row >> 1) & 3)) * 8);
  }

  f32x4 acc[4][8];
#pragma unroll
  for (int m = 0; m < 4; m++)
#pragma unroll
    for (int n = 0; n < 8; n++)
#pragma unroll
      for (int j = 0; j < 4; j++) acc[m][n][j] = 0.f;

  auto STAGE = [&](int kt, int buf) {
    bf16* sb = &lds[buf][0];
    int ko = kt * 32;
#pragma unroll
    for (int r = 0; r < 4; r++) gload16(aSrc[r] + ko, sb + r * 1024 + t * 8);
#pragma unroll
    for (int r = 0; r < 4; r++) gload16(bSrc[r] + ko, sb + 4096 + r * 1024 + t * 8);
  };

  STAGE(0, 0);
  __syncthreads();

  for (int kt = 0; kt < nk; kt++) {
    if (kt + 1 < nk) STAGE(kt + 1, (kt + 1) & 1);
    const bf16* sb = &lds[kt & 1][0];
    bf16x8 af[4], bfr[4];
#pragma unroll
    for (int m = 0; m < 4; m++) af[m] = *(const bf16x8*)(sb + aOff[m]);
    // B frags in two halves of 4 to cap register pressure (~220 peak)
#pragma unroll
    for (int n = 0; n < 4; n++) bfr[n] = *(const bf16x8*)(sb + bOff[n]);
#pragma unroll
    for (int m = 0; m < 4; m++)
#pragma unroll
      for (int n = 0; n < 4; n++)
        acc[m][n] = __builtin_amdgcn_mfma_f32_16x16x32_bf16(af[m], bfr[n], acc[m][n], 0, 0, 0);
#pragma unroll
    for (int n = 0; n < 4; n++) bfr[n] = *(const bf16x8*)(sb + bOff[4 + n]);
#pragma unroll
    for (int m = 0; m < 4; m++)
#pragma unroll
      for (int n = 0; n < 4; n++)
        acc[m][4 + n] = __builtin_amdgcn_mfma_f32_16x16x32_bf16(af[m], bfr[n], acc[m][4 + n], 0, 0, 0);
    __syncthreads();
  }

  int colb = n0 + l15;
  int rowb = wm * 64 + l4 * 4;
  float bia[8];
#pragma unroll
  for (int n = 0; n < 8; n++)
    bia[n] = (FIRST || kOff == 0) ? bias[(size_t)e * NPE + colb + n * 16] : 0.f;
  float* ybuf = FIRST ? nullptr : ((kOff == 0) ? y2a : y2b);
#pragma unroll
  for (int m = 0; m < 4; m++) {
#pragma unroll
    for (int jj = 0; jj < 4; jj++) {
      int gRow = row0 + rowb + m * 16 + jj;
      if (gRow < segEnd) {
        if (FIRST) {
#pragma unroll
          for (int n = 0; n < 8; n++) {
            float v = acc[m][n][jj] + bia[n];
            v = fmaxf(v, 0.f);
            hout[(size_t)gRow * HDIM + colb + n * 16] = (bf16)v;
          }
        } else {
          float pscale = ps[gRow];
          float* orow = ybuf + (size_t)tok[gRow] * DDIM;
#pragma unroll
          for (int n = 0; n < 8; n++) {
            float v = (acc[m][n][jj] + bia[n]) * pscale;
            atomicAdd(orow + colb + n * 16, v);  // 2 adds/elem/buf -> deterministic
          }
        }
      }
    }
  }
}

// ---------------- combine: out = y2a + y2b ----------------
__global__ void combine_kernel(const float* __restrict__ a, const float* __restrict__ b,
                               float* __restrict__ out) {
  int i = blockIdx.x * 256 + threadIdx.x;
  f32x4 va = ((const f32x4*)a)[i];
  f32x4 vb = ((const f32x4*)b)[i];
  ((f32x4*)out)[i] = va + vb;
}

extern "C" void kernel_launch(void* const* d_in, const int* in_sizes, int n_in,
                              void* d_out, int out_size, void* d_ws, size_t ws_size,
                              hipStream_t stream) {
  (void)in_sizes; (void)n_in; (void)out_size; (void)ws_size;
  const float* x  = (const float*)d_in[0];
  const float* Wg = (const float*)d_in[1];
  const float* W1 = (const float*)d_in[2];
  const float* b1 = (const float*)d_in[3];
  const float* W2 = (const float*)d_in[4];
  const float* b2 = (const float*)d_in[5];
  float* out = (float*)d_out;

  char* ws = (char*)d_ws;
  bf16*  xb   = (bf16*)(ws);                     //   8 MiB: [4096][1024] bf16
  bf16*  W1T  = (bf16*)(ws + (8ull  << 20));     //  32 MiB: [8][2048][1024] bf16
  bf16*  W2T  = (bf16*)(ws + (40ull << 20));     //  32 MiB: [8][1024][2048] bf16
  bf16*  hbuf = (bf16*)(ws + (72ull << 20));     //  32 MiB: [8192][2048] bf16
  float* y2a  = (float*)(ws + (104ull << 20));   //  16 MiB: [4096][1024] f32
  float* y2b  = (float*)(ws + (120ull << 20));   //  16 MiB: [4096][1024] f32
  char*  ext  = ws + (136ull << 20);
  int2*   ge      = (int2*)(ext);
  float2* gp      = (float2*)(ext + (64u  << 10));
  int*    tok     = (int*)(ext + (128u << 10));
  float*  psarr   = (float*)(ext + (160u << 10));
  int*    meta    = (int*)(ext + (224u << 10));

  transpose_cvt_kernel<<<dim3(64, 32, 8), 256, 0, stream>>>(W1, W1T, 1024, 2048);
  transpose_cvt_kernel<<<dim3(32, 64, 8), 256, 0, stream>>>(W2, W2T, 2048, 1024);
  gate_kernel<<<1024, 256, 0, stream>>>(x, Wg, ge, gp, xb, y2a, y2b);
  sort_kernel<<<1, 1024, 0, stream>>>(ge, gp, tok, psarr, meta);
  // per-XCD M-slots = ceil(71/8) = 9; grid = 9 * 16 * 8 = 1152 for both
  moe_gemm_kernel<true><<<dim3(1152), 128, 0, stream>>>(
      xb, W1T, b1, tok, psarr, meta, hbuf, nullptr, nullptr);
  moe_gemm_kernel<false><<<dim3(1152), 128, 0, stream>>>(
      hbuf, W2T, b2, tok, psarr, meta, nullptr, y2a, y2b);
  combine_kernel<<<4096, 256, 0, stream>>>(y2a, y2b, out);
}

// Round 16
// 252.612 us; speedup vs baseline: 1.2778x; 1.0263x over previous
//
#include <hip/hip_runtime.h>
#include <hip/hip_bf16.h>
#include <stdint.h>

typedef __bf16 bf16;
typedef __bf16 bf16x8 __attribute__((ext_vector_type(8)));
typedef __bf16 bf16x4 __attribute__((ext_vector_type(4)));
typedef float f32x4 __attribute__((ext_vector_type(4)));
typedef float f32x16 __attribute__((ext_vector_type(16)));

#define N_TOK 4096
#define DDIM 1024
#define HDIM 2048
#define NPAIR 8192

__device__ __forceinline__ void gload16(const void* g, void* l) {
  __builtin_amdgcn_global_load_lds(
      (const __attribute__((address_space(1))) unsigned int*)g,
      (__attribute__((address_space(3))) unsigned int*)l, 16, 0, 0);
}

// ------- per-expert transpose+convert: in [R][C] f32 -> out [C][R] bf16 -------
// R16: 64x64 tiles (16KB in / 8KB out per block, 4x fewer blocks), float4 in,
// bf16x8 out, 2-way-free LDS bank pattern both sides.
__global__ __launch_bounds__(256)
void transpose_cvt_kernel(const float* __restrict__ in, bf16* __restrict__ out,
                          int R, int C) {
  __shared__ float tile[64][65];
  const float* ip = in + (size_t)blockIdx.z * R * C;
  bf16* op = out + (size_t)blockIdx.z * R * C;
  int c0 = blockIdx.x * 64, r0 = blockIdx.y * 64;
  int t = threadIdx.x;
  int ir = t >> 2;              // 0..63 input row
  int icb = (t & 3) * 16;       // input col base
#pragma unroll
  for (int j = 0; j < 4; j++) {
    float4 v = *(const float4*)(ip + (size_t)(r0 + ir) * C + c0 + icb + j * 4);
    tile[ir][icb + j * 4 + 0] = v.x;
    tile[ir][icb + j * 4 + 1] = v.y;
    tile[ir][icb + j * 4 + 2] = v.z;
    tile[ir][icb + j * 4 + 3] = v.w;
  }
  __syncthreads();
  int oc = t >> 2;              // 0..63 output row (= input col)
  int orb = (t & 3) * 16;       // output col base (= input row)
#pragma unroll
  for (int s = 0; s < 2; s++) {
    bf16x8 o;
#pragma unroll
    for (int q = 0; q < 8; q++) o[q] = (bf16)tile[orb + s * 8 + q][oc];
    *(bf16x8*)(op + (size_t)(c0 + oc) * R + r0 + orb + s * 8) = o;
  }
}

// -- gating: fp32 logits, softmax, top-2; emits xb (bf16 x) and zeroes out rows --
__global__ void gate_kernel(const float* __restrict__ x, const float* __restrict__ Wg,
                            int2* __restrict__ ge, float2* __restrict__ gp,
                            bf16* __restrict__ xb, float* __restrict__ outp) {
  int t0 = blockIdx.x * 4;
  {
    float4 z = make_float4(0.f, 0.f, 0.f, 0.f);
    float4* ob = (float4*)(outp + (size_t)t0 * DDIM);
#pragma unroll
    for (int r = 0; r < 4; r++) ob[r * 256 + threadIdx.x] = z;
  }
  int t = t0 + (threadIdx.x >> 6);
  int lane = threadIdx.x & 63;
  const float* xr = x + (size_t)t * DDIM;
  bf16* xbr = xb + (size_t)t * DDIM;
  float a[8];
#pragma unroll
  for (int e = 0; e < 8; e++) a[e] = 0.f;
#pragma unroll
  for (int it = 0; it < 4; it++) {
    int d0 = it * 256 + lane * 4;
    float4 xv = *(const float4*)(xr + d0);
    bf16x4 o = {(bf16)xv.x, (bf16)xv.y, (bf16)xv.z, (bf16)xv.w};
    *(bf16x4*)(xbr + d0) = o;
    float xs[4] = {xv.x, xv.y, xv.z, xv.w};
#pragma unroll
    for (int dd = 0; dd < 4; dd++) {
      float4 w0 = *(const float4*)(Wg + (size_t)(d0 + dd) * 8);
      float4 w1 = *(const float4*)(Wg + (size_t)(d0 + dd) * 8 + 4);
      a[0] += xs[dd] * w0.x; a[1] += xs[dd] * w0.y; a[2] += xs[dd] * w0.z; a[3] += xs[dd] * w0.w;
      a[4] += xs[dd] * w1.x; a[5] += xs[dd] * w1.y; a[6] += xs[dd] * w1.z; a[7] += xs[dd] * w1.w;
    }
  }
#pragma unroll
  for (int off = 32; off >= 1; off >>= 1) {
#pragma unroll
    for (int e = 0; e < 8; e++) a[e] += __shfl_xor(a[e], off);
  }
  if (lane == 0) {
    float m = a[0];
#pragma unroll
    for (int e = 1; e < 8; e++) m = fmaxf(m, a[e]);
    float p[8]; float s = 0.f;
#pragma unroll
    for (int e = 0; e < 8; e++) { p[e] = expf(a[e] - m); s += p[e]; }
    float inv = 1.f / s;
    int i0 = 0; float v0 = a[0];
#pragma unroll
    for (int e = 1; e < 8; e++) if (a[e] > v0) { v0 = a[e]; i0 = e; }
    int i1 = -1; float v1 = -1e30f;
#pragma unroll
    for (int e = 0; e < 8; e++) if (e != i0 && a[e] > v1) { v1 = a[e]; i1 = e; }
    ge[t] = make_int2(i0, i1);
    gp[t] = make_float2(p[i0] * inv, p[i1] * inv);
  }
}

// ------- deterministic stable counting sort of 8192 pairs by expert (1 block) -------
// meta[0..8]=segment base; meta[9..16]=tileStart (BM=128), meta[17]=total128
__global__ void sort_kernel(const int2* __restrict__ ge, const float2* __restrict__ gp,
                            int* __restrict__ tok, float* __restrict__ ps,
                            int* __restrict__ meta) {
  __shared__ int hist[8], runn[8], wc[16][8], wb[16][8], baseS[9];
  int tid = threadIdx.x;
  int lane = tid & 63, wv = tid >> 6;
  if (tid < 8) hist[tid] = 0;
  __syncthreads();
  for (int i = tid; i < NPAIR; i += 1024) {
    int2 g = ge[i >> 1];
    int e = (i & 1) ? g.y : g.x;
    atomicAdd(&hist[e], 1);
  }
  __syncthreads();
  if (tid == 0) {
    int b = 0, ts1 = 0;
    for (int e = 0; e < 8; e++) {
      baseS[e] = b; meta[e] = b;
      meta[9 + e] = ts1;  ts1 += (hist[e] + 127) / 128;
      b += hist[e];
    }
    baseS[8] = b; meta[8] = b; meta[17] = ts1;
  }
  __syncthreads();
  if (tid < 8) runn[tid] = baseS[tid];
  __syncthreads();
  for (int c = 0; c < 8; c++) {
    int i = c * 1024 + tid;
    int2 g = ge[i >> 1];
    int e = (i & 1) ? g.y : g.x;
    int rank = 0;
#pragma unroll
    for (int ee = 0; ee < 8; ee++) {
      unsigned long long b = __ballot(e == ee);
      if (e == ee) rank = __popcll(b & ((1ull << lane) - 1ull));
      if (lane == 0) wc[wv][ee] = __popcll(b);
    }
    __syncthreads();
    if (tid < 8) {
      int s = runn[tid];
      for (int w = 0; w < 16; w++) { wb[w][tid] = s; s += wc[w][tid]; }
      runn[tid] = s;
    }
    __syncthreads();
    int pos = wb[wv][e] + rank;
    tok[pos] = i >> 1;
    float2 p2 = gp[i >> 1];
    ps[pos] = (i & 1) ? p2.y : p2.x;
    __syncthreads();
  }
}

// ---- grouped GEMM (R13 proven): BM=128, BN=128, BK=32, 256 thr, m97 no-asm loop ----
template <int KDIM, int NPE, bool FIRST, int NT>
__global__ __launch_bounds__(256, 4)
void moe_gemm_kernel(const bf16* __restrict__ A, const bf16* __restrict__ Bt,
                     const float* __restrict__ bias, const int* __restrict__ tok,
                     const float* __restrict__ ps, const int* __restrict__ meta,
                     bf16* __restrict__ hout, float* __restrict__ outp) {
  __shared__ bf16 lds[2][8192];
  constexpr int nk = KDIM / 32;

  int MTa = meta[17];
  int xcd = blockIdx.x & 7;
  int idx = blockIdx.x >> 3;
  int mLo = (MTa * xcd) >> 3;
  int mHi = (MTa * (xcd + 1)) >> 3;
  int cnt = mHi - mLo;
  if (idx >= cnt * NT) return;
  int tileN = idx / cnt;
  int tileM = mLo + idx - tileN * cnt;

  int e = 0;
#pragma unroll
  for (int k = 1; k < 8; k++) if (tileM >= meta[9 + k]) e = k;
  int row0 = meta[e] + (tileM - meta[9 + e]) * 128;
  int segEnd = meta[e + 1];
  int n0 = tileN * 128;

  int t = threadIdx.x;
  const bf16* aSrc[2];
  const bf16* bSrc[2];
  {
    int swz = ((t & 3) ^ ((t >> 3) & 3)) * 8;
#pragma unroll
    for (int r = 0; r < 2; r++) {
      int row = r * 64 + (t >> 2);
      int gRow = row0 + row; if (gRow > NPAIR - 1) gRow = NPAIR - 1;
      int arow = FIRST ? tok[gRow] : gRow;
      aSrc[r] = A + (size_t)arow * KDIM + swz;
      bSrc[r] = Bt + ((size_t)e * NPE + n0 + row) * KDIM + swz;
    }
  }

  int lane = t & 63, wv = t >> 6;
  int wm = wv >> 1, wn = wv & 1;
  int l15 = lane & 15, l4 = lane >> 4;
  int aOff[4], bOff[4];
#pragma unroll
  for (int m = 0; m < 4; m++) {
    int row = wm * 64 + m * 16 + l15;
    aOff[m] = row * 32 + ((l4 ^ ((row >> 1) & 3)) * 8);
  }
#pragma unroll
  for (int n = 0; n < 4; n++) {
    int row = wn * 64 + n * 16 + l15;
    bOff[n] = 4096 + row * 32 + ((l4 ^ ((row >> 1) & 3)) * 8);
  }

  f32x4 acc[4][4];
#pragma unroll
  for (int m = 0; m < 4; m++)
#pragma unroll
    for (int n = 0; n < 4; n++)
#pragma unroll
      for (int j = 0; j < 4; j++) acc[m][n][j] = 0.f;

  auto STAGE = [&](int kt, int buf) {
    bf16* sb = &lds[buf][0];
    int ko = kt * 32;
    gload16(aSrc[0] + ko, sb + t * 8);
    gload16(aSrc[1] + ko, sb + 2048 + t * 8);
    gload16(bSrc[0] + ko, sb + 4096 + t * 8);
    gload16(bSrc[1] + ko, sb + 6144 + t * 8);
  };

  STAGE(0, 0);
  __syncthreads();

  for (int kt = 0; kt < nk; kt++) {
    if (kt + 1 < nk) STAGE(kt + 1, (kt + 1) & 1);
    const bf16* sb = &lds[kt & 1][0];
    bf16x8 af[4], bfr[4];
#pragma unroll
    for (int m = 0; m < 4; m++) af[m] = *(const bf16x8*)(sb + aOff[m]);
#pragma unroll
    for (int n = 0; n < 4; n++) bfr[n] = *(const bf16x8*)(sb + bOff[n]);
#pragma unroll
    for (int m = 0; m < 4; m++)
#pragma unroll
      for (int n = 0; n < 4; n++)
        acc[m][n] = __builtin_amdgcn_mfma_f32_16x16x32_bf16(af[m], bfr[n], acc[m][n], 0, 0, 0);
    __syncthreads();
  }

  int colb = n0 + wn * 64 + l15;
  int rowb = wm * 64 + l4 * 4;
  float bia[4];
#pragma unroll
  for (int n = 0; n < 4; n++) bia[n] = bias[(size_t)e * NPE + colb + n * 16];
#pragma unroll
  for (int m = 0; m < 4; m++) {
#pragma unroll
    for (int jj = 0; jj < 4; jj++) {
      int gRow = row0 + rowb + m * 16 + jj;
      if (gRow < segEnd) {
        if (FIRST) {
#pragma unroll
          for (int n = 0; n < 4; n++) {
            float v = acc[m][n][jj] + bia[n];
            v = fmaxf(v, 0.f);
            hout[(size_t)gRow * NPE + colb + n * 16] = (bf16)v;
          }
        } else {
          float pscale = ps[gRow];
          float* orow = outp + (size_t)tok[gRow] * DDIM;
#pragma unroll
          for (int n = 0; n < 4; n++) {
            float v = (acc[m][n][jj] + bia[n]) * pscale;
            atomicAdd(orow + colb + n * 16, v);  // exactly 2 adds/elem -> deterministic
          }
        }
      }
    }
  }
}

// ---- BENCHMARK-ONLY: G1-shaped GEMM with 32x32x16 MFMA shape ----
// Same tile/staging/loop as R13; fragments/epilogue use the 32x32 layout:
// A: row = lane&31, k = (lane>>5)*8 (+ks*16); C/D: col=lane&31,
// row=(reg&3)+8*(reg>>2)+4*(lane>>5) [HW-verified m74/m101].
// Writes hbuf AFTER real G2 consumed it; real G1 rewrites before next use.
__global__ __launch_bounds__(256, 4)
void moe_gemm32_kernel(const bf16* __restrict__ A, const bf16* __restrict__ Bt,
                       const float* __restrict__ bias, const int* __restrict__ tok,
                       const int* __restrict__ meta, bf16* __restrict__ hout) {
  constexpr int KDIM = 1024, NPE = 2048, NT = 16, nk = 32;
  __shared__ bf16 lds[2][8192];

  int MTa = meta[17];
  int xcd = blockIdx.x & 7;
  int idx = blockIdx.x >> 3;
  int mLo = (MTa * xcd) >> 3;
  int mHi = (MTa * (xcd + 1)) >> 3;
  int cnt = mHi - mLo;
  if (idx >= cnt * NT) return;
  int tileN = idx / cnt;
  int tileM = mLo + idx - tileN * cnt;

  int e = 0;
#pragma unroll
  for (int k = 1; k < 8; k++) if (tileM >= meta[9 + k]) e = k;
  int row0 = meta[e] + (tileM - meta[9 + e]) * 128;
  int segEnd = meta[e + 1];
  int n0 = tileN * 128;

  int t = threadIdx.x;
  const bf16* aSrc[2];
  const bf16* bSrc[2];
  {
    int swz = ((t & 3) ^ ((t >> 3) & 3)) * 8;
#pragma unroll
    for (int r = 0; r < 2; r++) {
      int row = r * 64 + (t >> 2);
      int gRow = row0 + row; if (gRow > NPAIR - 1) gRow = NPAIR - 1;
      aSrc[r] = A + (size_t)tok[gRow] * KDIM + swz;
      bSrc[r] = Bt + ((size_t)e * NPE + n0 + row) * KDIM + swz;
    }
  }

  int lane = t & 63, wv = t >> 6;
  int wm = wv >> 1, wn = wv & 1;
  int l31 = lane & 31, l5 = lane >> 5;
  // frag element offsets: frag f (0,1), k-step ks (0,1): kc = ks*2 + l5
  int aOff[2][2], bOff[2][2];
#pragma unroll
  for (int f = 0; f < 2; f++)
#pragma unroll
    for (int ks = 0; ks < 2; ks++) {
      int arow = wm * 64 + f * 32 + l31;
      int brow = wn * 64 + f * 32 + l31;
      int kc = ks * 2 + l5;
      aOff[f][ks] = arow * 32 + ((kc ^ ((arow >> 1) & 3)) * 8);
      bOff[f][ks] = 4096 + brow * 32 + ((kc ^ ((brow >> 1) & 3)) * 8);
    }

  f32x16 acc[2][2];
#pragma unroll
  for (int m = 0; m < 2; m++)
#pragma unroll
    for (int n = 0; n < 2; n++)
#pragma unroll
      for (int j = 0; j < 16; j++) acc[m][n][j] = 0.f;

  auto STAGE = [&](int kt, int buf) {
    bf16* sb = &lds[buf][0];
    int ko = kt * 32;
    gload16(aSrc[0] + ko, sb + t * 8);
    gload16(aSrc[1] + ko, sb + 2048 + t * 8);
    gload16(bSrc[0] + ko, sb + 4096 + t * 8);
    gload16(bSrc[1] + ko, sb + 6144 + t * 8);
  };

  STAGE(0, 0);
  __syncthreads();

  for (int kt = 0; kt < nk; kt++) {
    if (kt + 1 < nk) STAGE(kt + 1, (kt + 1) & 1);
    const bf16* sb = &lds[kt & 1][0];
#pragma unroll
    for (int ks = 0; ks < 2; ks++) {
      bf16x8 af[2], bfr[2];
#pragma unroll
      for (int f = 0; f < 2; f++) {
        af[f] = *(const bf16x8*)(sb + aOff[f][ks]);
        bfr[f] = *(const bf16x8*)(sb + bOff[f][ks]);
      }
#pragma unroll
      for (int m = 0; m < 2; m++)
#pragma unroll
        for (int n = 0; n < 2; n++)
          acc[m][n] = __builtin_amdgcn_mfma_f32_32x32x16_bf16(af[m], bfr[n], acc[m][n], 0, 0, 0);
    }
    __syncthreads();
  }

  // epilogue: C/D col = lane&31, row = (reg&3) + 8*(reg>>2) + 4*(lane>>5)
#pragma unroll
  for (int m = 0; m < 2; m++) {
#pragma unroll
    for (int r = 0; r < 16; r++) {
      int crow = (r & 3) + 8 * (r >> 2) + 4 * l5;
      int gRow = row0 + wm * 64 + m * 32 + crow;
      if (gRow < segEnd) {
#pragma unroll
        for (int n = 0; n < 2; n++) {
          int col = n0 + wn * 64 + n * 32 + l31;
          float v = acc[m][n][r] + bias[(size_t)e * NPE + col];
          hout[(size_t)gRow * NPE + col] = (bf16)fmaxf(v, 0.f);
        }
      }
    }
  }
}

extern "C" void kernel_launch(void* const* d_in, const int* in_sizes, int n_in,
                              void* d_out, int out_size, void* d_ws, size_t ws_size,
                              hipStream_t stream) {
  (void)in_sizes; (void)n_in; (void)out_size; (void)ws_size;
  const float* x  = (const float*)d_in[0];
  const float* Wg = (const float*)d_in[1];
  const float* W1 = (const float*)d_in[2];
  const float* b1 = (const float*)d_in[3];
  const float* W2 = (const float*)d_in[4];
  const float* b2 = (const float*)d_in[5];
  float* out = (float*)d_out;

  char* ws = (char*)d_ws;
  bf16*  xb   = (bf16*)(ws);                     //   8 MiB: [4096][1024] bf16
  bf16*  W1T  = (bf16*)(ws + (8ull  << 20));     //  32 MiB: [8][2048][1024] bf16
  bf16*  W2T  = (bf16*)(ws + (40ull << 20));     //  32 MiB: [8][1024][2048] bf16
  bf16*  hbuf = (bf16*)(ws + (72ull << 20));     //  32 MiB: [8192][2048] bf16
  char*  ext  = ws + (104ull << 20);
  int2*   ge      = (int2*)(ext);
  float2* gp      = (float2*)(ext + (64u  << 10));
  int*    tok     = (int*)(ext + (128u << 10));
  float*  psarr   = (float*)(ext + (160u << 10));
  int*    meta    = (int*)(ext + (224u << 10));

  transpose_cvt_kernel<<<dim3(32, 16, 8), 256, 0, stream>>>(W1, W1T, 1024, 2048);
  transpose_cvt_kernel<<<dim3(16, 32, 8), 256, 0, stream>>>(W2, W2T, 2048, 1024);
  gate_kernel<<<1024, 256, 0, stream>>>(x, Wg, ge, gp, xb, out);
  sort_kernel<<<1, 1024, 0, stream>>>(ge, gp, tok, psarr, meta);
  // G1: NT=16 -> grid 9*16*8 = 1152 ; G2: NT=8 -> grid 9*8*8 = 576
  moe_gemm_kernel<1024, 2048, true, 16><<<dim3(1152), 256, 0, stream>>>(
      xb, W1T, b1, tok, psarr, meta, hbuf, nullptr);
  moe_gemm_kernel<2048, 1024, false, 8><<<dim3(576), 256, 0, stream>>>(
      hbuf, W2T, b2, tok, psarr, meta, nullptr, out);
  // benchmark-only 32x32-shape probe (hbuf is dead until next replay's G1 rewrites it)
  moe_gemm32_kernel<<<dim3(1152), 256, 0, stream>>>(xb, W1T, b1, tok, meta, hbuf);
}

// Round 17
// 205.081 us; speedup vs baseline: 1.5739x; 1.2318x over previous
//
#include <hip/hip_runtime.h>
#include <hip/hip_bf16.h>
#include <stdint.h>

typedef __bf16 bf16;
typedef __bf16 bf16x8 __attribute__((ext_vector_type(8)));
typedef __bf16 bf16x4 __attribute__((ext_vector_type(4)));
typedef float f32x4 __attribute__((ext_vector_type(4)));
typedef float f32x16 __attribute__((ext_vector_type(16)));

#define N_TOK 4096
#define DDIM 1024
#define HDIM 2048
#define NPAIR 8192

__device__ __forceinline__ void gload16(const void* g, void* l) {
  __builtin_amdgcn_global_load_lds(
      (const __attribute__((address_space(1))) unsigned int*)g,
      (__attribute__((address_space(3))) unsigned int*)l, 16, 0, 0);
}

// ------- per-expert transpose+convert: in [R][C] f32 -> out [C][R] bf16 -------
// 64x64 tiles (16KB in / 8KB out per block), float4 in, bf16x8 out.
__global__ __launch_bounds__(256)
void transpose_cvt_kernel(const float* __restrict__ in, bf16* __restrict__ out,
                          int R, int C) {
  __shared__ float tile[64][65];
  const float* ip = in + (size_t)blockIdx.z * R * C;
  bf16* op = out + (size_t)blockIdx.z * R * C;
  int c0 = blockIdx.x * 64, r0 = blockIdx.y * 64;
  int t = threadIdx.x;
  int ir = t >> 2;              // 0..63 input row
  int icb = (t & 3) * 16;       // input col base
#pragma unroll
  for (int j = 0; j < 4; j++) {
    float4 v = *(const float4*)(ip + (size_t)(r0 + ir) * C + c0 + icb + j * 4);
    tile[ir][icb + j * 4 + 0] = v.x;
    tile[ir][icb + j * 4 + 1] = v.y;
    tile[ir][icb + j * 4 + 2] = v.z;
    tile[ir][icb + j * 4 + 3] = v.w;
  }
  __syncthreads();
  int oc = t >> 2;              // 0..63 output row (= input col)
  int orb = (t & 3) * 16;       // output col base (= input row)
#pragma unroll
  for (int s = 0; s < 2; s++) {
    bf16x8 o;
#pragma unroll
    for (int q = 0; q < 8; q++) o[q] = (bf16)tile[orb + s * 8 + q][oc];
    *(bf16x8*)(op + (size_t)(c0 + oc) * R + r0 + orb + s * 8) = o;
  }
}

// -- gating: fp32 logits, softmax, top-2; emits xb (bf16 x) and zeroes out rows --
__global__ void gate_kernel(const float* __restrict__ x, const float* __restrict__ Wg,
                            int2* __restrict__ ge, float2* __restrict__ gp,
                            bf16* __restrict__ xb, float* __restrict__ outp) {
  int t0 = blockIdx.x * 4;
  {
    float4 z = make_float4(0.f, 0.f, 0.f, 0.f);
    float4* ob = (float4*)(outp + (size_t)t0 * DDIM);
#pragma unroll
    for (int r = 0; r < 4; r++) ob[r * 256 + threadIdx.x] = z;
  }
  int t = t0 + (threadIdx.x >> 6);
  int lane = threadIdx.x & 63;
  const float* xr = x + (size_t)t * DDIM;
  bf16* xbr = xb + (size_t)t * DDIM;
  float a[8];
#pragma unroll
  for (int e = 0; e < 8; e++) a[e] = 0.f;
#pragma unroll
  for (int it = 0; it < 4; it++) {
    int d0 = it * 256 + lane * 4;
    float4 xv = *(const float4*)(xr + d0);
    bf16x4 o = {(bf16)xv.x, (bf16)xv.y, (bf16)xv.z, (bf16)xv.w};
    *(bf16x4*)(xbr + d0) = o;
    float xs[4] = {xv.x, xv.y, xv.z, xv.w};
#pragma unroll
    for (int dd = 0; dd < 4; dd++) {
      float4 w0 = *(const float4*)(Wg + (size_t)(d0 + dd) * 8);
      float4 w1 = *(const float4*)(Wg + (size_t)(d0 + dd) * 8 + 4);
      a[0] += xs[dd] * w0.x; a[1] += xs[dd] * w0.y; a[2] += xs[dd] * w0.z; a[3] += xs[dd] * w0.w;
      a[4] += xs[dd] * w1.x; a[5] += xs[dd] * w1.y; a[6] += xs[dd] * w1.z; a[7] += xs[dd] * w1.w;
    }
  }
#pragma unroll
  for (int off = 32; off >= 1; off >>= 1) {
#pragma unroll
    for (int e = 0; e < 8; e++) a[e] += __shfl_xor(a[e], off);
  }
  if (lane == 0) {
    float m = a[0];
#pragma unroll
    for (int e = 1; e < 8; e++) m = fmaxf(m, a[e]);
    float p[8]; float s = 0.f;
#pragma unroll
    for (int e = 0; e < 8; e++) { p[e] = expf(a[e] - m); s += p[e]; }
    float inv = 1.f / s;
    int i0 = 0; float v0 = a[0];
#pragma unroll
    for (int e = 1; e < 8; e++) if (a[e] > v0) { v0 = a[e]; i0 = e; }
    int i1 = -1; float v1 = -1e30f;
#pragma unroll
    for (int e = 0; e < 8; e++) if (e != i0 && a[e] > v1) { v1 = a[e]; i1 = e; }
    ge[t] = make_int2(i0, i1);
    gp[t] = make_float2(p[i0] * inv, p[i1] * inv);
  }
}

// ------- deterministic stable counting sort of 8192 pairs by expert (1 block) -------
// meta[0..8]=segment base; meta[9..16]=tileStart (BM=128), meta[17]=total128
__global__ void sort_kernel(const int2* __restrict__ ge, const float2* __restrict__ gp,
                            int* __restrict__ tok, float* __restrict__ ps,
                            int* __restrict__ meta) {
  __shared__ int hist[8], runn[8], wc[16][8], wb[16][8], baseS[9];
  int tid = threadIdx.x;
  int lane = tid & 63, wv = tid >> 6;
  if (tid < 8) hist[tid] = 0;
  __syncthreads();
  for (int i = tid; i < NPAIR; i += 1024) {
    int2 g = ge[i >> 1];
    int e = (i & 1) ? g.y : g.x;
    atomicAdd(&hist[e], 1);
  }
  __syncthreads();
  if (tid == 0) {
    int b = 0, ts1 = 0;
    for (int e = 0; e < 8; e++) {
      baseS[e] = b; meta[e] = b;
      meta[9 + e] = ts1;  ts1 += (hist[e] + 127) / 128;
      b += hist[e];
    }
    baseS[8] = b; meta[8] = b; meta[17] = ts1;
  }
  __syncthreads();
  if (tid < 8) runn[tid] = baseS[tid];
  __syncthreads();
  for (int c = 0; c < 8; c++) {
    int i = c * 1024 + tid;
    int2 g = ge[i >> 1];
    int e = (i & 1) ? g.y : g.x;
    int rank = 0;
#pragma unroll
    for (int ee = 0; ee < 8; ee++) {
      unsigned long long b = __ballot(e == ee);
      if (e == ee) rank = __popcll(b & ((1ull << lane) - 1ull));
      if (lane == 0) wc[wv][ee] = __popcll(b);
    }
    __syncthreads();
    if (tid < 8) {
      int s = runn[tid];
      for (int w = 0; w < 16; w++) { wb[w][tid] = s; s += wc[w][tid]; }
      runn[tid] = s;
    }
    __syncthreads();
    int pos = wb[wv][e] + rank;
    tok[pos] = i >> 1;
    float2 p2 = gp[i >> 1];
    ps[pos] = (i & 1) ? p2.y : p2.x;
    __syncthreads();
  }
}

// ---- grouped GEMM: BM=128, BN=128, BK=32, 256 thr (4 waves 2x2), m97 no-asm loop ----
// R17: 32x32x16 MFMA shape (µbench 2382 vs 2075 TF; 8 MFMA ~64cyc vs 16 ~78cyc
// per wave per K-tile, same ds_read count). Per-wave out 64x64 = 2x2 frags of
// 32x32, acc f32x16[2][2]. Fragment reads stay conflict-free under the
// (row>>1)&3 chunk swizzle (each lane-octet covers all 8 16B-slots).
// A/B frag: row = lane&31, k-chunk = ks*2 + (lane>>5) (8 contiguous k/lane).
// C/D (HW-verified m74/m101): col = lane&31, row = (r&3)+8*(r>>2)+4*(lane>>5).
// FIRST: A=xb[tok[row]], Bt=W1T -> h = relu(A*B + b1), bf16
// !FIRST: A=h[row],      Bt=W2T -> atomicAdd(out[tok[row]], (A*B + b2)*ps[row])
template <int KDIM, int NPE, bool FIRST, int NT>
__global__ __launch_bounds__(256, 4)
void moe_gemm_kernel(const bf16* __restrict__ A, const bf16* __restrict__ Bt,
                     const float* __restrict__ bias, const int* __restrict__ tok,
                     const float* __restrict__ ps, const int* __restrict__ meta,
                     bf16* __restrict__ hout, float* __restrict__ outp) {
  __shared__ bf16 lds[2][8192];
  constexpr int nk = KDIM / 32;

  // runtime-balanced XCD-chunked mapping
  int MTa = meta[17];
  int xcd = blockIdx.x & 7;
  int idx = blockIdx.x >> 3;
  int mLo = (MTa * xcd) >> 3;
  int mHi = (MTa * (xcd + 1)) >> 3;
  int cnt = mHi - mLo;
  if (idx >= cnt * NT) return;
  int tileN = idx / cnt;
  int tileM = mLo + idx - tileN * cnt;

  int e = 0;
#pragma unroll
  for (int k = 1; k < 8; k++) if (tileM >= meta[9 + k]) e = k;
  int row0 = meta[e] + (tileM - meta[9 + e]) * 128;
  int segEnd = meta[e + 1];
  int n0 = tileN * 128;

  int t = threadIdx.x;
  const bf16* aSrc[2];
  const bf16* bSrc[2];
  {
    int swz = ((t & 3) ^ ((t >> 3) & 3)) * 8;
#pragma unroll
    for (int r = 0; r < 2; r++) {
      int row = r * 64 + (t >> 2);
      int gRow = row0 + row; if (gRow > NPAIR - 1) gRow = NPAIR - 1;
      int arow = FIRST ? tok[gRow] : gRow;
      aSrc[r] = A + (size_t)arow * KDIM + swz;
      bSrc[r] = Bt + ((size_t)e * NPE + n0 + row) * KDIM + swz;
    }
  }

  int lane = t & 63, wv = t >> 6;
  int wm = wv >> 1, wn = wv & 1;  // 2x2 waves; per-wave out 64x64
  int l31 = lane & 31, l5 = lane >> 5;
  // fragment element offsets: frag f (0,1), k-step ks (0,1): k-chunk = ks*2+l5
  int aOff[2][2], bOff[2][2];
#pragma unroll
  for (int f = 0; f < 2; f++)
#pragma unroll
    for (int ks = 0; ks < 2; ks++) {
      int arow = wm * 64 + f * 32 + l31;
      int brow = wn * 64 + f * 32 + l31;
      int kc = ks * 2 + l5;
      aOff[f][ks] = arow * 32 + ((kc ^ ((arow >> 1) & 3)) * 8);
      bOff[f][ks] = 4096 + brow * 32 + ((kc ^ ((brow >> 1) & 3)) * 8);
    }

  f32x16 acc[2][2];
#pragma unroll
  for (int m = 0; m < 2; m++)
#pragma unroll
    for (int n = 0; n < 2; n++)
#pragma unroll
      for (int j = 0; j < 16; j++) acc[m][n][j] = 0.f;

  auto STAGE = [&](int kt, int buf) {
    bf16* sb = &lds[buf][0];
    int ko = kt * 32;
    gload16(aSrc[0] + ko, sb + t * 8);
    gload16(aSrc[1] + ko, sb + 2048 + t * 8);
    gload16(bSrc[0] + ko, sb + 4096 + t * 8);
    gload16(bSrc[1] + ko, sb + 6144 + t * 8);
  };

  STAGE(0, 0);
  __syncthreads();

  for (int kt = 0; kt < nk; kt++) {
    if (kt + 1 < nk) STAGE(kt + 1, (kt + 1) & 1);
    const bf16* sb = &lds[kt & 1][0];
#pragma unroll
    for (int ks = 0; ks < 2; ks++) {
      bf16x8 af[2], bfr[2];
#pragma unroll
      for (int f = 0; f < 2; f++) {
        af[f] = *(const bf16x8*)(sb + aOff[f][ks]);
        bfr[f] = *(const bf16x8*)(sb + bOff[f][ks]);
      }
#pragma unroll
      for (int m = 0; m < 2; m++)
#pragma unroll
        for (int n = 0; n < 2; n++)
          acc[m][n] = __builtin_amdgcn_mfma_f32_32x32x16_bf16(af[m], bfr[n], acc[m][n], 0, 0, 0);
    }
    __syncthreads();
  }

  // epilogue: C/D col = lane&31, row = (r&3) + 8*(r>>2) + 4*(lane>>5)
  float bia[2];
#pragma unroll
  for (int n = 0; n < 2; n++)
    bia[n] = bias[(size_t)e * NPE + n0 + wn * 64 + n * 32 + l31];
#pragma unroll
  for (int m = 0; m < 2; m++) {
#pragma unroll
    for (int r = 0; r < 16; r++) {
      int crow = (r & 3) + 8 * (r >> 2) + 4 * l5;
      int gRow = row0 + wm * 64 + m * 32 + crow;
      if (gRow < segEnd) {
        if (FIRST) {
#pragma unroll
          for (int n = 0; n < 2; n++) {
            int col = n0 + wn * 64 + n * 32 + l31;
            float v = acc[m][n][r] + bia[n];
            hout[(size_t)gRow * NPE + col] = (bf16)fmaxf(v, 0.f);
          }
        } else {
          float pscale = ps[gRow];
          float* orow = outp + (size_t)tok[gRow] * DDIM;
#pragma unroll
          for (int n = 0; n < 2; n++) {
            int col = n0 + wn * 64 + n * 32 + l31;
            float v = (acc[m][n][r] + bia[n]) * pscale;
            atomicAdd(orow + col, v);  // exactly 2 adds/elem -> deterministic
          }
        }
      }
    }
  }
}

extern "C" void kernel_launch(void* const* d_in, const int* in_sizes, int n_in,
                              void* d_out, int out_size, void* d_ws, size_t ws_size,
                              hipStream_t stream) {
  (void)in_sizes; (void)n_in; (void)out_size; (void)ws_size;
  const float* x  = (const float*)d_in[0];
  const float* Wg = (const float*)d_in[1];
  const float* W1 = (const float*)d_in[2];
  const float* b1 = (const float*)d_in[3];
  const float* W2 = (const float*)d_in[4];
  const float* b2 = (const float*)d_in[5];
  float* out = (float*)d_out;

  char* ws = (char*)d_ws;
  bf16*  xb   = (bf16*)(ws);                     //   8 MiB: [4096][1024] bf16
  bf16*  W1T  = (bf16*)(ws + (8ull  << 20));     //  32 MiB: [8][2048][1024] bf16
  bf16*  W2T  = (bf16*)(ws + (40ull << 20));     //  32 MiB: [8][1024][2048] bf16
  bf16*  hbuf = (bf16*)(ws + (72ull << 20));     //  32 MiB: [8192][2048] bf16
  char*  ext  = ws + (104ull << 20);
  int2*   ge      = (int2*)(ext);
  float2* gp      = (float2*)(ext + (64u  << 10));
  int*    tok     = (int*)(ext + (128u << 10));
  float*  psarr   = (float*)(ext + (160u << 10));
  int*    meta    = (int*)(ext + (224u << 10));

  transpose_cvt_kernel<<<dim3(32, 16, 8), 256, 0, stream>>>(W1, W1T, 1024, 2048);
  transpose_cvt_kernel<<<dim3(16, 32, 8), 256, 0, stream>>>(W2, W2T, 2048, 1024);
  gate_kernel<<<1024, 256, 0, stream>>>(x, Wg, ge, gp, xb, out);
  sort_kernel<<<1, 1024, 0, stream>>>(ge, gp, tok, psarr, meta);
  // per-XCD M-slots = ceil(71/8) = 9
  // G1: NT=16 (HDIM/128) -> grid 9*16*8 = 1152
  moe_gemm_kernel<1024, 2048, true, 16><<<dim3(1152), 256, 0, stream>>>(
      xb, W1T, b1, tok, psarr, meta, hbuf, nullptr);
  // G2: NT=8 (DDIM/128) -> grid 9*8*8 = 576
  moe_gemm_kernel<2048, 1024, false, 8><<<dim3(576), 256, 0, stream>>>(
      hbuf, W2T, b2, tok, psarr, meta, nullptr, out);
}

// Round 18
// 195.765 us; speedup vs baseline: 1.6488x; 1.0476x over previous
//
#include <hip/hip_runtime.h>
#include <hip/hip_bf16.h>
#include <stdint.h>

typedef __bf16 bf16;
typedef __bf16 bf16x8 __attribute__((ext_vector_type(8)));
typedef __bf16 bf16x4 __attribute__((ext_vector_type(4)));
typedef float f32x4 __attribute__((ext_vector_type(4)));

#define N_TOK 4096
#define DDIM 1024
#define HDIM 2048
#define NPAIR 8192

__device__ __forceinline__ void gload16(const void* g, void* l) {
  __builtin_amdgcn_global_load_lds(
      (const __attribute__((address_space(1))) unsigned int*)g,
      (__attribute__((address_space(3))) unsigned int*)l, 16, 0, 0);
}

// ------- per-expert transpose+convert: in [R][C] f32 -> out [C][R] bf16 -------
// 64x64 tiles (16KB in / 8KB out per block), float4 in, bf16x8 out.
__global__ __launch_bounds__(256)
void transpose_cvt_kernel(const float* __restrict__ in, bf16* __restrict__ out,
                          int R, int C) {
  __shared__ float tile[64][65];
  const float* ip = in + (size_t)blockIdx.z * R * C;
  bf16* op = out + (size_t)blockIdx.z * R * C;
  int c0 = blockIdx.x * 64, r0 = blockIdx.y * 64;
  int t = threadIdx.x;
  int ir = t >> 2;              // 0..63 input row
  int icb = (t & 3) * 16;       // input col base
#pragma unroll
  for (int j = 0; j < 4; j++) {
    float4 v = *(const float4*)(ip + (size_t)(r0 + ir) * C + c0 + icb + j * 4);
    tile[ir][icb + j * 4 + 0] = v.x;
    tile[ir][icb + j * 4 + 1] = v.y;
    tile[ir][icb + j * 4 + 2] = v.z;
    tile[ir][icb + j * 4 + 3] = v.w;
  }
  __syncthreads();
  int oc = t >> 2;              // 0..63 output row (= input col)
  int orb = (t & 3) * 16;       // output col base (= input row)
#pragma unroll
  for (int s = 0; s < 2; s++) {
    bf16x8 o;
#pragma unroll
    for (int q = 0; q < 8; q++) o[q] = (bf16)tile[orb + s * 8 + q][oc];
    *(bf16x8*)(op + (size_t)(c0 + oc) * R + r0 + orb + s * 8) = o;
  }
}

// -- gating: fp32 logits, softmax, top-2; emits xb (bf16 x) and zeroes out rows --
__global__ void gate_kernel(const float* __restrict__ x, const float* __restrict__ Wg,
                            int2* __restrict__ ge, float2* __restrict__ gp,
                            bf16* __restrict__ xb, float* __restrict__ outp) {
  int t0 = blockIdx.x * 4;
  {
    float4 z = make_float4(0.f, 0.f, 0.f, 0.f);
    float4* ob = (float4*)(outp + (size_t)t0 * DDIM);
#pragma unroll
    for (int r = 0; r < 4; r++) ob[r * 256 + threadIdx.x] = z;
  }
  int t = t0 + (threadIdx.x >> 6);
  int lane = threadIdx.x & 63;
  const float* xr = x + (size_t)t * DDIM;
  bf16* xbr = xb + (size_t)t * DDIM;
  float a[8];
#pragma unroll
  for (int e = 0; e < 8; e++) a[e] = 0.f;
#pragma unroll
  for (int it = 0; it < 4; it++) {
    int d0 = it * 256 + lane * 4;
    float4 xv = *(const float4*)(xr + d0);
    bf16x4 o = {(bf16)xv.x, (bf16)xv.y, (bf16)xv.z, (bf16)xv.w};
    *(bf16x4*)(xbr + d0) = o;
    float xs[4] = {xv.x, xv.y, xv.z, xv.w};
#pragma unroll
    for (int dd = 0; dd < 4; dd++) {
      float4 w0 = *(const float4*)(Wg + (size_t)(d0 + dd) * 8);
      float4 w1 = *(const float4*)(Wg + (size_t)(d0 + dd) * 8 + 4);
      a[0] += xs[dd] * w0.x; a[1] += xs[dd] * w0.y; a[2] += xs[dd] * w0.z; a[3] += xs[dd] * w0.w;
      a[4] += xs[dd] * w1.x; a[5] += xs[dd] * w1.y; a[6] += xs[dd] * w1.z; a[7] += xs[dd] * w1.w;
    }
  }
#pragma unroll
  for (int off = 32; off >= 1; off >>= 1) {
#pragma unroll
    for (int e = 0; e < 8; e++) a[e] += __shfl_xor(a[e], off);
  }
  if (lane == 0) {
    float m = a[0];
#pragma unroll
    for (int e = 1; e < 8; e++) m = fmaxf(m, a[e]);
    float p[8]; float s = 0.f;
#pragma unroll
    for (int e = 0; e < 8; e++) { p[e] = expf(a[e] - m); s += p[e]; }
    float inv = 1.f / s;
    int i0 = 0; float v0 = a[0];
#pragma unroll
    for (int e = 1; e < 8; e++) if (a[e] > v0) { v0 = a[e]; i0 = e; }
    int i1 = -1; float v1 = -1e30f;
#pragma unroll
    for (int e = 0; e < 8; e++) if (e != i0 && a[e] > v1) { v1 = a[e]; i1 = e; }
    ge[t] = make_int2(i0, i1);
    gp[t] = make_float2(p[i0] * inv, p[i1] * inv);
  }
}

// ------- deterministic stable counting sort of 8192 pairs by expert (1 block) -------
// meta[0..8]=segment base; meta[9..16]=tileStart (BM=128), meta[17]=total128
__global__ void sort_kernel(const int2* __restrict__ ge, const float2* __restrict__ gp,
                            int* __restrict__ tok, float* __restrict__ ps,
                            int* __restrict__ meta) {
  __shared__ int hist[8], runn[8], wc[16][8], wb[16][8], baseS[9];
  int tid = threadIdx.x;
  int lane = tid & 63, wv = tid >> 6;
  if (tid < 8) hist[tid] = 0;
  __syncthreads();
  for (int i = tid; i < NPAIR; i += 1024) {
    int2 g = ge[i >> 1];
    int e = (i & 1) ? g.y : g.x;
    atomicAdd(&hist[e], 1);
  }
  __syncthreads();
  if (tid == 0) {
    int b = 0, ts1 = 0;
    for (int e = 0; e < 8; e++) {
      baseS[e] = b; meta[e] = b;
      meta[9 + e] = ts1;  ts1 += (hist[e] + 127) / 128;
      b += hist[e];
    }
    baseS[8] = b; meta[8] = b; meta[17] = ts1;
  }
  __syncthreads();
  if (tid < 8) runn[tid] = baseS[tid];
  __syncthreads();
  for (int c = 0; c < 8; c++) {
    int i = c * 1024 + tid;
    int2 g = ge[i >> 1];
    int e = (i & 1) ? g.y : g.x;
    int rank = 0;
#pragma unroll
    for (int ee = 0; ee < 8; ee++) {
      unsigned long long b = __ballot(e == ee);
      if (e == ee) rank = __popcll(b & ((1ull << lane) - 1ull));
      if (lane == 0) wc[wv][ee] = __popcll(b);
    }
    __syncthreads();
    if (tid < 8) {
      int s = runn[tid];
      for (int w = 0; w < 16; w++) { wb[w][tid] = s; s += wc[w][tid]; }
      runn[tid] = s;
    }
    __syncthreads();
    int pos = wb[wv][e] + rank;
    tok[pos] = i >> 1;
    float2 p2 = gp[i >> 1];
    ps[pos] = (i & 1) ? p2.y : p2.x;
    __syncthreads();
  }
}

// ---- grouped GEMM (banked best): BM=128, BN=128, BK=32, 256 thr (4 waves 2x2) ----
// m97-style no-asm double-buffered loop; 16x16x32 MFMA (conflict-free reads
// under the (row>>1)&3 chunk swizzle — 32x32 shape measured 4.39M conflicts,
// reverted). T2 swizzle via pre-swizzled global source; XCD-chunked map.
// FIRST: A=xb[tok[row]], Bt=W1T -> h = relu(A*B + b1), bf16
// !FIRST: A=h[row],      Bt=W2T -> atomicAdd(out[tok[row]], (A*B + b2)*ps[row])
template <int KDIM, int NPE, bool FIRST, int NT>
__global__ __launch_bounds__(256, 4)
void moe_gemm_kernel(const bf16* __restrict__ A, const bf16* __restrict__ Bt,
                     const float* __restrict__ bias, const int* __restrict__ tok,
                     const float* __restrict__ ps, const int* __restrict__ meta,
                     bf16* __restrict__ hout, float* __restrict__ outp) {
  __shared__ bf16 lds[2][8192];
  constexpr int nk = KDIM / 32;

  // runtime-balanced XCD-chunked mapping
  int MTa = meta[17];
  int xcd = blockIdx.x & 7;
  int idx = blockIdx.x >> 3;
  int mLo = (MTa * xcd) >> 3;
  int mHi = (MTa * (xcd + 1)) >> 3;
  int cnt = mHi - mLo;
  if (idx >= cnt * NT) return;
  int tileN = idx / cnt;
  int tileM = mLo + idx - tileN * cnt;

  int e = 0;
#pragma unroll
  for (int k = 1; k < 8; k++) if (tileM >= meta[9 + k]) e = k;
  int row0 = meta[e] + (tileM - meta[9 + e]) * 128;
  int segEnd = meta[e + 1];
  int n0 = tileN * 128;

  int t = threadIdx.x;
  const bf16* aSrc[2];
  const bf16* bSrc[2];
  {
    int swz = ((t & 3) ^ ((t >> 3) & 3)) * 8;
#pragma unroll
    for (int r = 0; r < 2; r++) {
      int row = r * 64 + (t >> 2);
      int gRow = row0 + row; if (gRow > NPAIR - 1) gRow = NPAIR - 1;
      int arow = FIRST ? tok[gRow] : gRow;
      aSrc[r] = A + (size_t)arow * KDIM + swz;
      bSrc[r] = Bt + ((size_t)e * NPE + n0 + row) * KDIM + swz;
    }
  }

  int lane = t & 63, wv = t >> 6;
  int wm = wv >> 1, wn = wv & 1;  // 2x2 waves; per-wave out 64x64
  int l15 = lane & 15, l4 = lane >> 4;
  int aOff[4], bOff[4];
#pragma unroll
  for (int m = 0; m < 4; m++) {
    int row = wm * 64 + m * 16 + l15;
    aOff[m] = row * 32 + ((l4 ^ ((row >> 1) & 3)) * 8);
  }
#pragma unroll
  for (int n = 0; n < 4; n++) {
    int row = wn * 64 + n * 16 + l15;
    bOff[n] = 4096 + row * 32 + ((l4 ^ ((row >> 1) & 3)) * 8);
  }

  f32x4 acc[4][4];
#pragma unroll
  for (int m = 0; m < 4; m++)
#pragma unroll
    for (int n = 0; n < 4; n++)
#pragma unroll
      for (int j = 0; j < 4; j++) acc[m][n][j] = 0.f;

  auto STAGE = [&](int kt, int buf) {
    bf16* sb = &lds[buf][0];
    int ko = kt * 32;
    gload16(aSrc[0] + ko, sb + t * 8);
    gload16(aSrc[1] + ko, sb + 2048 + t * 8);
    gload16(bSrc[0] + ko, sb + 4096 + t * 8);
    gload16(bSrc[1] + ko, sb + 6144 + t * 8);
  };

  STAGE(0, 0);
  __syncthreads();

  for (int kt = 0; kt < nk; kt++) {
    if (kt + 1 < nk) STAGE(kt + 1, (kt + 1) & 1);
    const bf16* sb = &lds[kt & 1][0];
    bf16x8 af[4], bfr[4];
#pragma unroll
    for (int m = 0; m < 4; m++) af[m] = *(const bf16x8*)(sb + aOff[m]);
#pragma unroll
    for (int n = 0; n < 4; n++) bfr[n] = *(const bf16x8*)(sb + bOff[n]);
#pragma unroll
    for (int m = 0; m < 4; m++)
#pragma unroll
      for (int n = 0; n < 4; n++)
        acc[m][n] = __builtin_amdgcn_mfma_f32_16x16x32_bf16(af[m], bfr[n], acc[m][n], 0, 0, 0);
    __syncthreads();
  }

  int colb = n0 + wn * 64 + l15;
  int rowb = wm * 64 + l4 * 4;
  float bia[4];
#pragma unroll
  for (int n = 0; n < 4; n++) bia[n] = bias[(size_t)e * NPE + colb + n * 16];
#pragma unroll
  for (int m = 0; m < 4; m++) {
#pragma unroll
    for (int jj = 0; jj < 4; jj++) {
      int gRow = row0 + rowb + m * 16 + jj;
      if (gRow < segEnd) {
        if (FIRST) {
#pragma unroll
          for (int n = 0; n < 4; n++) {
            float v = acc[m][n][jj] + bia[n];
            v = fmaxf(v, 0.f);
            hout[(size_t)gRow * NPE + colb + n * 16] = (bf16)v;
          }
        } else {
          float pscale = ps[gRow];
          float* orow = outp + (size_t)tok[gRow] * DDIM;
#pragma unroll
          for (int n = 0; n < 4; n++) {
            float v = (acc[m][n][jj] + bia[n]) * pscale;
            atomicAdd(orow + colb + n * 16, v);  // exactly 2 adds/elem -> deterministic
          }
        }
      }
    }
  }
}

extern "C" void kernel_launch(void* const* d_in, const int* in_sizes, int n_in,
                              void* d_out, int out_size, void* d_ws, size_t ws_size,
                              hipStream_t stream) {
  (void)in_sizes; (void)n_in; (void)out_size; (void)ws_size;
  const float* x  = (const float*)d_in[0];
  const float* Wg = (const float*)d_in[1];
  const float* W1 = (const float*)d_in[2];
  const float* b1 = (const float*)d_in[3];
  const float* W2 = (const float*)d_in[4];
  const float* b2 = (const float*)d_in[5];
  float* out = (float*)d_out;

  char* ws = (char*)d_ws;
  bf16*  xb   = (bf16*)(ws);                     //   8 MiB: [4096][1024] bf16
  bf16*  W1T  = (bf16*)(ws + (8ull  << 20));     //  32 MiB: [8][2048][1024] bf16
  bf16*  W2T  = (bf16*)(ws + (40ull << 20));     //  32 MiB: [8][1024][2048] bf16
  bf16*  hbuf = (bf16*)(ws + (72ull << 20));     //  32 MiB: [8192][2048] bf16
  char*  ext  = ws + (104ull << 20);
  int2*   ge      = (int2*)(ext);
  float2* gp      = (float2*)(ext + (64u  << 10));
  int*    tok     = (int*)(ext + (128u << 10));
  float*  psarr   = (float*)(ext + (160u << 10));
  int*    meta    = (int*)(ext + (224u << 10));

  transpose_cvt_kernel<<<dim3(32, 16, 8), 256, 0, stream>>>(W1, W1T, 1024, 2048);
  transpose_cvt_kernel<<<dim3(16, 32, 8), 256, 0, stream>>>(W2, W2T, 2048, 1024);
  gate_kernel<<<1024, 256, 0, stream>>>(x, Wg, ge, gp, xb, out);
  sort_kernel<<<1, 1024, 0, stream>>>(ge, gp, tok, psarr, meta);
  // per-XCD M-slots = ceil(71/8) = 9
  // G1: NT=16 (HDIM/128) -> grid 9*16*8 = 1152
  moe_gemm_kernel<1024, 2048, true, 16><<<dim3(1152), 256, 0, stream>>>(
      xb, W1T, b1, tok, psarr, meta, hbuf, nullptr);
  // G2: NT=8 (DDIM/128) -> grid 9*8*8 = 576
  moe_gemm_kernel<2048, 1024, false, 8><<<dim3(576), 256, 0, stream>>>(
      hbuf, W2T, b2, tok, psarr, meta, nullptr, out);
}